// Round 1
// baseline (1007.500 us; speedup 1.0000x reference)
//
#include <hip/hip_runtime.h>
#include <stdint.h>

typedef unsigned int uint;
typedef unsigned short ushort;

__device__ inline float bf2f(uint s) {
    union { uint u; float f; } x; x.u = s << 16; return x.f;
}
__device__ inline ushort f2bf(float f) {
    union { float f; uint u; } x; x.f = f;
    uint r = (x.u + 0x7fffu + ((x.u >> 16) & 1u)) >> 16;
    return (ushort)r;
}

// ---------------------------------------------------------------------------
// Fused linear: y = x @ W[j] + b[j] for j in {q,k,v,skip}; grid.y selects W.
// 64 rows x 128 cols per block, fp32, W + x^T staged in LDS. k,v stored bf16.
// ---------------------------------------------------------------------------
__global__ __launch_bounds__(256) void lin_kernel(
    const float* __restrict__ x,
    const float* __restrict__ W0, const float* __restrict__ b0,
    const float* __restrict__ W1, const float* __restrict__ b1,
    const float* __restrict__ W2, const float* __restrict__ b2,
    const float* __restrict__ W3, const float* __restrict__ b3,
    float* __restrict__ qout, ushort* __restrict__ kout,
    ushort* __restrict__ vout, float* __restrict__ sout, int n)
{
    __shared__ float xs[64][68];    // [k][row], +4 pad
    __shared__ float ws[64][128];   // [k][col]
    const int j = blockIdx.y;
    const float* W = (j==0) ? W0 : (j==1) ? W1 : (j==2) ? W2 : W3;
    const float* b = (j==0) ? b0 : (j==1) ? b1 : (j==2) ? b2 : b3;
    const int row0 = blockIdx.x * 64;
    const int tid = threadIdx.x;
    const int ty = tid >> 4, tx = tid & 15;
    const int r0 = ty * 4, c0 = tx * 8;

    float acc[4][8];
    #pragma unroll
    for (int r = 0; r < 4; ++r)
        #pragma unroll
        for (int c = 0; c < 8; ++c) acc[r][c] = 0.f;

    for (int kc = 0; kc < 128; kc += 64) {
        #pragma unroll
        for (int i = 0; i < 4; ++i) {               // x tile -> xs (transposed)
            int slot = i * 256 + tid;
            int rl = slot >> 4;
            int k4 = (slot & 15) << 2;
            float4 xv = make_float4(0.f, 0.f, 0.f, 0.f);
            int gr = row0 + rl;
            if (gr < n) xv = *(const float4*)&x[(size_t)gr * 128 + kc + k4];
            xs[k4 + 0][rl] = xv.x; xs[k4 + 1][rl] = xv.y;
            xs[k4 + 2][rl] = xv.z; xs[k4 + 3][rl] = xv.w;
        }
        #pragma unroll
        for (int i = 0; i < 8; ++i) {               // W tile -> ws
            int slot = i * 256 + tid;
            int kr = slot >> 5;
            int c4 = (slot & 31) << 2;
            *(float4*)&ws[kr][c4] = *(const float4*)&W[(size_t)(kc + kr) * 128 + c4];
        }
        __syncthreads();
        #pragma unroll 4
        for (int k = 0; k < 64; ++k) {
            float4 xv = *(const float4*)&xs[k][r0];
            float4 wa = *(const float4*)&ws[k][c0];
            float4 wb = *(const float4*)&ws[k][c0 + 4];
            float xr[4] = {xv.x, xv.y, xv.z, xv.w};
            float wr[8] = {wa.x, wa.y, wa.z, wa.w, wb.x, wb.y, wb.z, wb.w};
            #pragma unroll
            for (int r = 0; r < 4; ++r)
                #pragma unroll
                for (int c = 0; c < 8; ++c)
                    acc[r][c] = fmaf(xr[r], wr[c], acc[r][c]);
        }
        __syncthreads();
    }

    float bias[8];
    #pragma unroll
    for (int c = 0; c < 8; ++c) bias[c] = b[c0 + c];

    #pragma unroll
    for (int r = 0; r < 4; ++r) {
        int gr = row0 + r0 + r;
        if (gr >= n) continue;
        float o[8];
        #pragma unroll
        for (int c = 0; c < 8; ++c) o[c] = acc[r][c] + bias[c];
        if (j == 0 || j == 3) {
            float* dst = (j == 0) ? qout : sout;
            *(float4*)&dst[(size_t)gr * 128 + c0]     = make_float4(o[0], o[1], o[2], o[3]);
            *(float4*)&dst[(size_t)gr * 128 + c0 + 4] = make_float4(o[4], o[5], o[6], o[7]);
        } else {
            ushort* dst = (j == 1) ? kout : vout;
            uint p0 = (uint)f2bf(o[0]) | ((uint)f2bf(o[1]) << 16);
            uint p1 = (uint)f2bf(o[2]) | ((uint)f2bf(o[3]) << 16);
            uint p2 = (uint)f2bf(o[4]) | ((uint)f2bf(o[5]) << 16);
            uint p3 = (uint)f2bf(o[6]) | ((uint)f2bf(o[7]) << 16);
            *(uint4*)&dst[(size_t)gr * 128 + c0] = make_uint4(p0, p1, p2, p3);
        }
    }
}

// ---------------------------------------------------------------------------
// t[n,h,d] = sum_c We[d, h*32+c] * q[n, h*32+c]  — one wave per node,
// lane = h*16 + d. Replaces the per-edge (edge_attr @ We) GEMM.
// ---------------------------------------------------------------------------
__global__ __launch_bounds__(256) void t_kernel(const float* __restrict__ q,
                                                const float* __restrict__ We,
                                                float* __restrict__ t, int n)
{
    int wid = (blockIdx.x * blockDim.x + threadIdx.x) >> 6;
    int lane = threadIdx.x & 63;
    if (wid >= n) return;
    int h = lane >> 4, d = lane & 15;
    const float* qp = q + (size_t)wid * 128 + h * 32;
    const float* wp = We + (size_t)d * 128 + h * 32;
    float s = 0.f;
    #pragma unroll
    for (int c4 = 0; c4 < 8; ++c4) {
        float4 a = *(const float4*)&qp[c4 * 4];
        float4 b = *(const float4*)&wp[c4 * 4];
        s += a.x * b.x + a.y * b.y + a.z * b.z + a.w * b.w;
    }
    t[(size_t)wid * 64 + lane] = s;
}

// ---------------------------------------------------------------------------
// CSR build: histogram -> scan (3 kernels) -> scatter
// ---------------------------------------------------------------------------
__global__ void hist_kernel(const int* __restrict__ rows, int* __restrict__ counts, int e)
{
    int i = blockIdx.x * blockDim.x + threadIdx.x;
    if (i < e) atomicAdd(&counts[rows[i]], 1);
}

__global__ __launch_bounds__(1024) void scan1_kernel(int* __restrict__ data,
                                                     int* __restrict__ bsum, int n)
{
    __shared__ int s[1024];
    int i = blockIdx.x * 1024 + threadIdx.x;
    int v = (i < n) ? data[i] : 0;
    s[threadIdx.x] = v;
    __syncthreads();
    for (int offd = 1; offd < 1024; offd <<= 1) {
        int add = (threadIdx.x >= offd) ? s[threadIdx.x - offd] : 0;
        __syncthreads();
        s[threadIdx.x] += add;
        __syncthreads();
    }
    if (i < n) data[i] = s[threadIdx.x];
    if (threadIdx.x == 1023) bsum[blockIdx.x] = s[1023];
}

__global__ void scan2_kernel(const int* __restrict__ bsum, int* __restrict__ bofs, int nb)
{
    if (threadIdx.x == 0 && blockIdx.x == 0) {
        int a = 0;
        for (int i = 0; i < nb; ++i) { bofs[i] = a; a += bsum[i]; }
    }
}

__global__ __launch_bounds__(1024) void scan3_kernel(const int* __restrict__ incl,
                                                     const int* __restrict__ bofs,
                                                     int* __restrict__ offsets, int n)
{
    int i = blockIdx.x * 1024 + threadIdx.x;
    if (i == 0) offsets[0] = 0;
    if (i < n) offsets[i + 1] = incl[i] + bofs[blockIdx.x];
}

__global__ void scatter_kernel(const int* __restrict__ rows, const int* __restrict__ offsets,
                               int* __restrict__ cursor, int* __restrict__ elist, int e)
{
    int i = blockIdx.x * blockDim.x + threadIdx.x;
    if (i < e) {
        int r = rows[i];
        int p = atomicAdd(&cursor[r], 1);
        elist[offsets[r] + p] = i;
    }
}

// ---------------------------------------------------------------------------
// Aggregation: one wave per destination node. Lane l owns channels 2l,2l+1.
// Per-edge logit via 16-lane butterfly per head; softmax without max-shift
// (exactly invariant; logits are ~0.3 magnitude); fused beta-gate epilogue.
// ---------------------------------------------------------------------------
__global__ __launch_bounds__(256) void agg_kernel(
    const float* __restrict__ q, const ushort* __restrict__ kbf,
    const ushort* __restrict__ vbf, const float* __restrict__ t,
    const float* __restrict__ xskip, const float* __restrict__ ea,
    const int* __restrict__ cols, const int* __restrict__ offsets,
    const int* __restrict__ elist, const float* __restrict__ Wbeta,
    float* __restrict__ out, int n)
{
    int wid = (blockIdx.x * blockDim.x + threadIdx.x) >> 6;
    int lane = threadIdx.x & 63;
    if (wid >= n) return;
    const int d = lane & 15;
    const float2 qv = *(const float2*)&q[(size_t)wid * 128 + 2 * lane];
    const float tl = t[(size_t)wid * 64 + lane];
    const int beg = offsets[wid], end = offsets[wid + 1];
    const float scale = 0.17677669529663687f;  // 1/sqrt(32)

    float denom = 0.f, acc0 = 0.f, acc1 = 0.f;
    for (int i = beg; i < end; ++i) {
        int e = elist[i];
        int src = cols[e];
        uint kp = *(const uint*)&kbf[(size_t)src * 128 + 2 * lane];
        float eav = ea[(size_t)e * 16 + d];
        float part = qv.x * bf2f(kp & 0xffffu) + qv.y * bf2f(kp >> 16) + eav * tl;
        part += __shfl_xor(part, 1);
        part += __shfl_xor(part, 2);
        part += __shfl_xor(part, 4);
        part += __shfl_xor(part, 8);
        float p = __expf(part * scale);
        uint vp = *(const uint*)&vbf[(size_t)src * 128 + 2 * lane];
        denom += p;
        acc0 += p * bf2f(vp & 0xffffu);
        acc1 += p * bf2f(vp >> 16);
    }

    float inv = 1.f / (denom + 1e-16f);
    float o0 = acc0 * inv, o1 = acc1 * inv;
    float2 xs = *(const float2*)&xskip[(size_t)wid * 128 + 2 * lane];

    float bp = o0 * Wbeta[2 * lane] + o1 * Wbeta[2 * lane + 1]
             + xs.x * Wbeta[128 + 2 * lane] + xs.y * Wbeta[128 + 2 * lane + 1]
             + (o0 - xs.x) * Wbeta[256 + 2 * lane] + (o1 - xs.y) * Wbeta[256 + 2 * lane + 1];
    bp += __shfl_xor(bp, 1);
    bp += __shfl_xor(bp, 2);
    bp += __shfl_xor(bp, 4);
    bp += __shfl_xor(bp, 8);
    bp += __shfl_xor(bp, 16);
    bp += __shfl_xor(bp, 32);
    float beta = 1.f / (1.f + __expf(-bp));

    float r0 = beta * xs.x + (1.f - beta) * o0;
    float r1 = beta * xs.y + (1.f - beta) * o1;
    *(float2*)&out[(size_t)wid * 128 + 2 * lane] = make_float2(r0, r1);
}

// ---------------------------------------------------------------------------
extern "C" void kernel_launch(void* const* d_in, const int* in_sizes, int n_in,
                              void* d_out, int out_size, void* d_ws, size_t ws_size,
                              hipStream_t stream)
{
    const float* x     = (const float*)d_in[0];
    const float* ea    = (const float*)d_in[1];
    const int*   ei    = (const int*)d_in[2];   // [0:E)=row(dst), [E:2E)=col(src)
    const float* Wq    = (const float*)d_in[3];
    const float* bq    = (const float*)d_in[4];
    const float* Wk    = (const float*)d_in[5];
    const float* bk    = (const float*)d_in[6];
    const float* Wv    = (const float*)d_in[7];
    const float* bv    = (const float*)d_in[8];
    const float* We    = (const float*)d_in[9];
    const float* Wsk   = (const float*)d_in[10];
    const float* bsk   = (const float*)d_in[11];
    const float* Wbeta = (const float*)d_in[12];
    float* out = (float*)d_out;

    const int N = in_sizes[0] / 128;
    const int E = in_sizes[1] / 16;

    char* base = (char*)d_ws;
    size_t off = 0;
    auto alloc = [&](size_t bytes) -> void* {
        void* p = base + off;
        off += (bytes + 255) & ~(size_t)255;
        return p;
    };
    int*    tmp     = (int*)alloc((size_t)N * 4);        // counts -> inclusive scan
    int*    cursor  = (int*)alloc((size_t)N * 4);
    int*    offsets = (int*)alloc((size_t)(N + 1) * 4);
    int*    bsum    = (int*)alloc(4096 * 4);
    int*    bofs    = (int*)alloc(4096 * 4);
    int*    elist   = (int*)alloc((size_t)E * 4);
    float*  qbuf    = (float*)alloc((size_t)N * 128 * 4);
    float*  sbuf    = (float*)alloc((size_t)N * 128 * 4);
    float*  tbuf    = (float*)alloc((size_t)N * 64 * 4);
    ushort* kbuf    = (ushort*)alloc((size_t)N * 128 * 2);
    ushort* vbuf    = (ushort*)alloc((size_t)N * 128 * 2);
    (void)ws_size; (void)n_in; (void)out_size;

    hipMemsetAsync(tmp, 0, (size_t)N * 4, stream);
    hipMemsetAsync(cursor, 0, (size_t)N * 4, stream);

    dim3 lgrid((N + 63) / 64, 4);
    lin_kernel<<<lgrid, 256, 0, stream>>>(x, Wq, bq, Wk, bk, Wv, bv, Wsk, bsk,
                                          qbuf, kbuf, vbuf, sbuf, N);
    t_kernel<<<(N + 3) / 4, 256, 0, stream>>>(qbuf, We, tbuf, N);
    hist_kernel<<<(E + 255) / 256, 256, 0, stream>>>(ei, tmp, E);
    int nb = (N + 1023) / 1024;
    scan1_kernel<<<nb, 1024, 0, stream>>>(tmp, bsum, N);
    scan2_kernel<<<1, 64, 0, stream>>>(bsum, bofs, nb);
    scan3_kernel<<<nb, 1024, 0, stream>>>(tmp, bofs, offsets, N);
    scatter_kernel<<<(E + 255) / 256, 256, 0, stream>>>(ei, offsets, cursor, elist, E);
    agg_kernel<<<(N + 3) / 4, 256, 0, stream>>>(qbuf, kbuf, vbuf, tbuf, sbuf, ea,
                                                ei + E, offsets, elist, Wbeta, out, N);
}

// Round 2
// 851.464 us; speedup vs baseline: 1.1833x; 1.1833x over previous
//
#include <hip/hip_runtime.h>
#include <stdint.h>

typedef unsigned int uint;
typedef unsigned short ushort;

__device__ inline float bf2f(uint s) {
    union { uint u; float f; } x; x.u = s << 16; return x.f;
}
__device__ inline ushort f2bf(float f) {
    union { float f; uint u; } x; x.f = f;
    uint r = (x.u + 0x7fffu + ((x.u >> 16) & 1u)) >> 16;
    return (ushort)r;
}

// ---------------------------------------------------------------------------
// Fused linear: y = x @ W[j] + b[j] for j in {q,k,v,skip}; grid.y selects W.
// 64 rows x 128 cols per block, fp32, W + x^T staged in LDS.
// k,v are written bf16-packed and INTERLEAVED into one kv buffer:
//   kv[node*128 + 2*l]   = bf16x2 of k channels (2l, 2l+1)
//   kv[node*128 + 2*l+1] = bf16x2 of v channels (2l, 2l+1)
// so agg fetches both with one dwordx2 per lane per edge.
// ---------------------------------------------------------------------------
__global__ __launch_bounds__(256) void lin_kernel(
    const float* __restrict__ x,
    const float* __restrict__ W0, const float* __restrict__ b0,
    const float* __restrict__ W1, const float* __restrict__ b1,
    const float* __restrict__ W2, const float* __restrict__ b2,
    const float* __restrict__ W3, const float* __restrict__ b3,
    float* __restrict__ qout, uint* __restrict__ kvout,
    float* __restrict__ sout, int n)
{
    __shared__ float xs[64][68];    // [k][row], +4 pad
    __shared__ float ws[64][128];   // [k][col]
    const int j = blockIdx.y;
    const float* W = (j==0) ? W0 : (j==1) ? W1 : (j==2) ? W2 : W3;
    const float* b = (j==0) ? b0 : (j==1) ? b1 : (j==2) ? b2 : b3;
    const int row0 = blockIdx.x * 64;
    const int tid = threadIdx.x;
    const int ty = tid >> 4, tx = tid & 15;
    const int r0 = ty * 4, c0 = tx * 8;

    float acc[4][8];
    #pragma unroll
    for (int r = 0; r < 4; ++r)
        #pragma unroll
        for (int c = 0; c < 8; ++c) acc[r][c] = 0.f;

    for (int kc = 0; kc < 128; kc += 64) {
        #pragma unroll
        for (int i = 0; i < 4; ++i) {               // x tile -> xs (transposed)
            int slot = i * 256 + tid;
            int rl = slot >> 4;
            int k4 = (slot & 15) << 2;
            float4 xv = make_float4(0.f, 0.f, 0.f, 0.f);
            int gr = row0 + rl;
            if (gr < n) xv = *(const float4*)&x[(size_t)gr * 128 + kc + k4];
            xs[k4 + 0][rl] = xv.x; xs[k4 + 1][rl] = xv.y;
            xs[k4 + 2][rl] = xv.z; xs[k4 + 3][rl] = xv.w;
        }
        #pragma unroll
        for (int i = 0; i < 8; ++i) {               // W tile -> ws
            int slot = i * 256 + tid;
            int kr = slot >> 5;
            int c4 = (slot & 31) << 2;
            *(float4*)&ws[kr][c4] = *(const float4*)&W[(size_t)(kc + kr) * 128 + c4];
        }
        __syncthreads();
        #pragma unroll 4
        for (int k = 0; k < 64; ++k) {
            float4 xv = *(const float4*)&xs[k][r0];
            float4 wa = *(const float4*)&ws[k][c0];
            float4 wb = *(const float4*)&ws[k][c0 + 4];
            float xr[4] = {xv.x, xv.y, xv.z, xv.w};
            float wr[8] = {wa.x, wa.y, wa.z, wa.w, wb.x, wb.y, wb.z, wb.w};
            #pragma unroll
            for (int r = 0; r < 4; ++r)
                #pragma unroll
                for (int c = 0; c < 8; ++c)
                    acc[r][c] = fmaf(xr[r], wr[c], acc[r][c]);
        }
        __syncthreads();
    }

    float bias[8];
    #pragma unroll
    for (int c = 0; c < 8; ++c) bias[c] = b[c0 + c];

    #pragma unroll
    for (int r = 0; r < 4; ++r) {
        int gr = row0 + r0 + r;
        if (gr >= n) continue;
        float o[8];
        #pragma unroll
        for (int c = 0; c < 8; ++c) o[c] = acc[r][c] + bias[c];
        if (j == 0 || j == 3) {
            float* dst = (j == 0) ? qout : sout;
            *(float4*)&dst[(size_t)gr * 128 + c0]     = make_float4(o[0], o[1], o[2], o[3]);
            *(float4*)&dst[(size_t)gr * 128 + c0 + 4] = make_float4(o[4], o[5], o[6], o[7]);
        } else {
            // interleaved kv: k pairs at even uint slots, v pairs at odd
            uint* dst = kvout + (size_t)gr * 128 + c0 + ((j == 2) ? 1 : 0);
            dst[0] = (uint)f2bf(o[0]) | ((uint)f2bf(o[1]) << 16);
            dst[2] = (uint)f2bf(o[2]) | ((uint)f2bf(o[3]) << 16);
            dst[4] = (uint)f2bf(o[4]) | ((uint)f2bf(o[5]) << 16);
            dst[6] = (uint)f2bf(o[6]) | ((uint)f2bf(o[7]) << 16);
        }
    }
}

// ---------------------------------------------------------------------------
// t[n,h,d] = sum_c We[d, h*32+c] * q[n, h*32+c]  — one wave per node,
// lane = h*16 + d. Replaces the per-edge (edge_attr @ We) GEMM.
// ---------------------------------------------------------------------------
__global__ __launch_bounds__(256) void t_kernel(const float* __restrict__ q,
                                                const float* __restrict__ We,
                                                float* __restrict__ t, int n)
{
    int wid = (blockIdx.x * blockDim.x + threadIdx.x) >> 6;
    int lane = threadIdx.x & 63;
    if (wid >= n) return;
    int h = lane >> 4, d = lane & 15;
    const float* qp = q + (size_t)wid * 128 + h * 32;
    const float* wp = We + (size_t)d * 128 + h * 32;
    float s = 0.f;
    #pragma unroll
    for (int c4 = 0; c4 < 8; ++c4) {
        float4 a = *(const float4*)&qp[c4 * 4];
        float4 b = *(const float4*)&wp[c4 * 4];
        s += a.x * b.x + a.y * b.y + a.z * b.z + a.w * b.w;
    }
    t[(size_t)wid * 64 + lane] = s;
}

// ---------------------------------------------------------------------------
// CSR build: histogram -> scan (3 kernels) -> scatter
// ---------------------------------------------------------------------------
__global__ void hist_kernel(const int* __restrict__ rows, int* __restrict__ counts, int e)
{
    int i = blockIdx.x * blockDim.x + threadIdx.x;
    if (i < e) atomicAdd(&counts[rows[i]], 1);
}

__global__ __launch_bounds__(1024) void scan1_kernel(int* __restrict__ data,
                                                     int* __restrict__ bsum, int n)
{
    __shared__ int s[1024];
    int i = blockIdx.x * 1024 + threadIdx.x;
    int v = (i < n) ? data[i] : 0;
    s[threadIdx.x] = v;
    __syncthreads();
    for (int offd = 1; offd < 1024; offd <<= 1) {
        int add = (threadIdx.x >= offd) ? s[threadIdx.x - offd] : 0;
        __syncthreads();
        s[threadIdx.x] += add;
        __syncthreads();
    }
    if (i < n) data[i] = s[threadIdx.x];
    if (threadIdx.x == 1023) bsum[blockIdx.x] = s[1023];
}

__global__ void scan2_kernel(const int* __restrict__ bsum, int* __restrict__ bofs, int nb)
{
    if (threadIdx.x == 0 && blockIdx.x == 0) {
        int a = 0;
        for (int i = 0; i < nb; ++i) { bofs[i] = a; a += bsum[i]; }
    }
}

__global__ __launch_bounds__(1024) void scan3_kernel(const int* __restrict__ incl,
                                                     const int* __restrict__ bofs,
                                                     int* __restrict__ offsets, int n)
{
    int i = blockIdx.x * 1024 + threadIdx.x;
    if (i == 0) offsets[0] = 0;
    if (i < n) offsets[i + 1] = incl[i] + bofs[blockIdx.x];
}

// Writes src node AND edge id in CSR order — agg then has no indirection.
__global__ void scatter_kernel(const int* __restrict__ rows, const int* __restrict__ cols,
                               const int* __restrict__ offsets, int* __restrict__ cursor,
                               int* __restrict__ csr_src, int* __restrict__ csr_eid, int e)
{
    int i = blockIdx.x * blockDim.x + threadIdx.x;
    if (i < e) {
        int r = rows[i];
        int p = atomicAdd(&cursor[r], 1);
        int pos = offsets[r] + p;
        csr_src[pos] = cols[i];
        csr_eid[pos] = i;
    }
}

// ---------------------------------------------------------------------------
// Aggregation: one wave per destination node. Lane l owns channels 2l,2l+1.
// Edges processed in chunks of 8: all 16 gathers (kv + ea) issued as
// independent loads before any consumption -> latency amortized 8x.
// ---------------------------------------------------------------------------
#define AGG_U 8

__global__ __launch_bounds__(256) void agg_kernel(
    const float* __restrict__ q, const uint* __restrict__ kv,
    const float* __restrict__ t, const float* __restrict__ xskip,
    const float* __restrict__ ea, const int* __restrict__ csr_src,
    const int* __restrict__ csr_eid, const int* __restrict__ offsets,
    const float* __restrict__ Wbeta, float* __restrict__ out, int n)
{
    int wid = (blockIdx.x * blockDim.x + threadIdx.x) >> 6;
    int lane = threadIdx.x & 63;
    if (wid >= n) return;
    const int d = lane & 15;
    const float2 qv = *(const float2*)&q[(size_t)wid * 128 + 2 * lane];
    const float tl = t[(size_t)wid * 64 + lane];
    const int beg = offsets[wid], end = offsets[wid + 1];
    const float scale = 0.17677669529663687f;  // 1/sqrt(32)

    float denom = 0.f, acc0 = 0.f, acc1 = 0.f;

    for (int i = beg; i < end; i += AGG_U) {
        const int rem = end - i;
        int srcs[AGG_U], eids[AGG_U];
        #pragma unroll
        for (int u = 0; u < AGG_U; ++u) {
            int idx = i + ((u < rem) ? u : 0);   // clamp: tail loads duplicate edge 0
            srcs[u] = csr_src[idx];
            eids[u] = csr_eid[idx];
        }
        uint2 kvp[AGG_U];
        float eav[AGG_U];
        #pragma unroll
        for (int u = 0; u < AGG_U; ++u) {
            kvp[u] = *(const uint2*)&kv[(size_t)srcs[u] * 128 + 2 * lane];
            eav[u] = ea[(size_t)eids[u] * 16 + d];
        }
        #pragma unroll
        for (int u = 0; u < AGG_U; ++u) {
            if (u < rem) {
                float part = qv.x * bf2f(kvp[u].x & 0xffffu)
                           + qv.y * bf2f(kvp[u].x >> 16)
                           + eav[u] * tl;
                part += __shfl_xor(part, 1);
                part += __shfl_xor(part, 2);
                part += __shfl_xor(part, 4);
                part += __shfl_xor(part, 8);
                float p = __expf(part * scale);
                denom += p;
                acc0 += p * bf2f(kvp[u].y & 0xffffu);
                acc1 += p * bf2f(kvp[u].y >> 16);
            }
        }
    }

    float inv = 1.f / (denom + 1e-16f);
    float o0 = acc0 * inv, o1 = acc1 * inv;
    float2 xs = *(const float2*)&xskip[(size_t)wid * 128 + 2 * lane];

    float bp = o0 * Wbeta[2 * lane] + o1 * Wbeta[2 * lane + 1]
             + xs.x * Wbeta[128 + 2 * lane] + xs.y * Wbeta[128 + 2 * lane + 1]
             + (o0 - xs.x) * Wbeta[256 + 2 * lane] + (o1 - xs.y) * Wbeta[256 + 2 * lane + 1];
    bp += __shfl_xor(bp, 1);
    bp += __shfl_xor(bp, 2);
    bp += __shfl_xor(bp, 4);
    bp += __shfl_xor(bp, 8);
    bp += __shfl_xor(bp, 16);
    bp += __shfl_xor(bp, 32);
    float beta = 1.f / (1.f + __expf(-bp));

    float r0 = beta * xs.x + (1.f - beta) * o0;
    float r1 = beta * xs.y + (1.f - beta) * o1;
    *(float2*)&out[(size_t)wid * 128 + 2 * lane] = make_float2(r0, r1);
}

// ---------------------------------------------------------------------------
extern "C" void kernel_launch(void* const* d_in, const int* in_sizes, int n_in,
                              void* d_out, int out_size, void* d_ws, size_t ws_size,
                              hipStream_t stream)
{
    const float* x     = (const float*)d_in[0];
    const float* ea    = (const float*)d_in[1];
    const int*   ei    = (const int*)d_in[2];   // [0:E)=row(dst), [E:2E)=col(src)
    const float* Wq    = (const float*)d_in[3];
    const float* bq    = (const float*)d_in[4];
    const float* Wk    = (const float*)d_in[5];
    const float* bk    = (const float*)d_in[6];
    const float* Wv    = (const float*)d_in[7];
    const float* bv    = (const float*)d_in[8];
    const float* We    = (const float*)d_in[9];
    const float* Wsk   = (const float*)d_in[10];
    const float* bsk   = (const float*)d_in[11];
    const float* Wbeta = (const float*)d_in[12];
    float* out = (float*)d_out;

    const int N = in_sizes[0] / 128;
    const int E = in_sizes[1] / 16;

    char* base = (char*)d_ws;
    size_t off = 0;
    auto alloc = [&](size_t bytes) -> void* {
        void* p = base + off;
        off += (bytes + 255) & ~(size_t)255;
        return p;
    };
    int*    tmp     = (int*)alloc((size_t)N * 4);        // counts -> inclusive scan
    int*    cursor  = (int*)alloc((size_t)N * 4);
    int*    offsets = (int*)alloc((size_t)(N + 1) * 4);
    int*    bsum    = (int*)alloc(4096 * 4);
    int*    bofs    = (int*)alloc(4096 * 4);
    int*    csr_src = (int*)alloc((size_t)E * 4);
    int*    csr_eid = (int*)alloc((size_t)E * 4);
    float*  qbuf    = (float*)alloc((size_t)N * 128 * 4);
    float*  sbuf    = (float*)alloc((size_t)N * 128 * 4);
    float*  tbuf    = (float*)alloc((size_t)N * 64 * 4);
    uint*   kvbuf   = (uint*)alloc((size_t)N * 128 * 4); // interleaved bf16x2 k|v
    (void)ws_size; (void)n_in; (void)out_size;

    hipMemsetAsync(tmp, 0, (size_t)N * 4, stream);
    hipMemsetAsync(cursor, 0, (size_t)N * 4, stream);

    dim3 lgrid((N + 63) / 64, 4);
    lin_kernel<<<lgrid, 256, 0, stream>>>(x, Wq, bq, Wk, bk, Wv, bv, Wsk, bsk,
                                          qbuf, kvbuf, sbuf, N);
    t_kernel<<<(N + 3) / 4, 256, 0, stream>>>(qbuf, We, tbuf, N);
    hist_kernel<<<(E + 255) / 256, 256, 0, stream>>>(ei, tmp, E);
    int nb = (N + 1023) / 1024;
    scan1_kernel<<<nb, 1024, 0, stream>>>(tmp, bsum, N);
    scan2_kernel<<<1, 64, 0, stream>>>(bsum, bofs, nb);
    scan3_kernel<<<nb, 1024, 0, stream>>>(tmp, bofs, offsets, N);
    scatter_kernel<<<(E + 255) / 256, 256, 0, stream>>>(ei, ei + E, offsets, cursor,
                                                        csr_src, csr_eid, E);
    agg_kernel<<<(N + 3) / 4, 256, 0, stream>>>(qbuf, kvbuf, tbuf, sbuf, ea,
                                                csr_src, csr_eid, offsets, Wbeta, out, N);
}

// Round 3
// 808.092 us; speedup vs baseline: 1.2468x; 1.0537x over previous
//
#include <hip/hip_runtime.h>
#include <stdint.h>

typedef unsigned int uint;
typedef unsigned short ushort;

__device__ inline float bflo(uint u) {  // low bf16 of pair -> f32
    union { uint x; float f; } z; z.x = u << 16; return z.f;
}
__device__ inline float bfhi(uint u) {  // high bf16 of pair -> f32
    union { uint x; float f; } z; z.x = u & 0xffff0000u; return z.f;
}
__device__ inline ushort f2bf(float f) {
    union { float f; uint u; } x; x.f = f;
    uint r = (x.u + 0x7fffu + ((x.u >> 16) & 1u)) >> 16;
    return (ushort)r;
}

// ---------------------------------------------------------------------------
// Fused linear: y = x @ W[j] + b[j] for j in {q,k,v,skip}; grid.y selects W.
// 64 rows x 128 cols per block, fp32, W + x^T staged in LDS.
// k,v are written bf16-packed into one kv buffer per node row (128 uints):
//   [0..63]   = k channel-pairs (pair j = channels 2j,2j+1)
//   [64..127] = v channel-pairs
// ---------------------------------------------------------------------------
__global__ __launch_bounds__(256) void lin_kernel(
    const float* __restrict__ x,
    const float* __restrict__ W0, const float* __restrict__ b0,
    const float* __restrict__ W1, const float* __restrict__ b1,
    const float* __restrict__ W2, const float* __restrict__ b2,
    const float* __restrict__ W3, const float* __restrict__ b3,
    float* __restrict__ qout, uint* __restrict__ kvout,
    float* __restrict__ sout, int n)
{
    __shared__ float xs[64][68];    // [k][row], +4 pad
    __shared__ float ws[64][128];   // [k][col]
    const int j = blockIdx.y;
    const float* W = (j==0) ? W0 : (j==1) ? W1 : (j==2) ? W2 : W3;
    const float* b = (j==0) ? b0 : (j==1) ? b1 : (j==2) ? b2 : b3;
    const int row0 = blockIdx.x * 64;
    const int tid = threadIdx.x;
    const int ty = tid >> 4, tx = tid & 15;
    const int r0 = ty * 4, c0 = tx * 8;

    float acc[4][8];
    #pragma unroll
    for (int r = 0; r < 4; ++r)
        #pragma unroll
        for (int c = 0; c < 8; ++c) acc[r][c] = 0.f;

    for (int kc = 0; kc < 128; kc += 64) {
        #pragma unroll
        for (int i = 0; i < 4; ++i) {               // x tile -> xs (transposed)
            int slot = i * 256 + tid;
            int rl = slot >> 4;
            int k4 = (slot & 15) << 2;
            float4 xv = make_float4(0.f, 0.f, 0.f, 0.f);
            int gr = row0 + rl;
            if (gr < n) xv = *(const float4*)&x[(size_t)gr * 128 + kc + k4];
            xs[k4 + 0][rl] = xv.x; xs[k4 + 1][rl] = xv.y;
            xs[k4 + 2][rl] = xv.z; xs[k4 + 3][rl] = xv.w;
        }
        #pragma unroll
        for (int i = 0; i < 8; ++i) {               // W tile -> ws
            int slot = i * 256 + tid;
            int kr = slot >> 5;
            int c4 = (slot & 31) << 2;
            *(float4*)&ws[kr][c4] = *(const float4*)&W[(size_t)(kc + kr) * 128 + c4];
        }
        __syncthreads();
        #pragma unroll 4
        for (int k = 0; k < 64; ++k) {
            float4 xv = *(const float4*)&xs[k][r0];
            float4 wa = *(const float4*)&ws[k][c0];
            float4 wb = *(const float4*)&ws[k][c0 + 4];
            float xr[4] = {xv.x, xv.y, xv.z, xv.w};
            float wr[8] = {wa.x, wa.y, wa.z, wa.w, wb.x, wb.y, wb.z, wb.w};
            #pragma unroll
            for (int r = 0; r < 4; ++r)
                #pragma unroll
                for (int c = 0; c < 8; ++c)
                    acc[r][c] = fmaf(xr[r], wr[c], acc[r][c]);
        }
        __syncthreads();
    }

    float bias[8];
    #pragma unroll
    for (int c = 0; c < 8; ++c) bias[c] = b[c0 + c];

    #pragma unroll
    for (int r = 0; r < 4; ++r) {
        int gr = row0 + r0 + r;
        if (gr >= n) continue;
        float o[8];
        #pragma unroll
        for (int c = 0; c < 8; ++c) o[c] = acc[r][c] + bias[c];
        if (j == 0 || j == 3) {
            float* dst = (j == 0) ? qout : sout;
            *(float4*)&dst[(size_t)gr * 128 + c0]     = make_float4(o[0], o[1], o[2], o[3]);
            *(float4*)&dst[(size_t)gr * 128 + c0 + 4] = make_float4(o[4], o[5], o[6], o[7]);
        } else {
            // de-interleaved kv: k pairs in [0..63], v pairs in [64..127]
            uint* dst = kvout + (size_t)gr * 128 + ((j == 2) ? 64 : 0) + (c0 >> 1);
            uint p0 = (uint)f2bf(o[0]) | ((uint)f2bf(o[1]) << 16);
            uint p1 = (uint)f2bf(o[2]) | ((uint)f2bf(o[3]) << 16);
            uint p2 = (uint)f2bf(o[4]) | ((uint)f2bf(o[5]) << 16);
            uint p3 = (uint)f2bf(o[6]) | ((uint)f2bf(o[7]) << 16);
            *(uint4*)dst = make_uint4(p0, p1, p2, p3);
        }
    }
}

// ---------------------------------------------------------------------------
// t[n,h,d] = sum_c We[d, h*32+c] * q[n, h*32+c]  — one wave per node,
// lane = h*16 + d. Replaces the per-edge (edge_attr @ We) GEMM.
// ---------------------------------------------------------------------------
__global__ __launch_bounds__(256) void t_kernel(const float* __restrict__ q,
                                                const float* __restrict__ We,
                                                float* __restrict__ t, int n)
{
    int wid = (blockIdx.x * blockDim.x + threadIdx.x) >> 6;
    int lane = threadIdx.x & 63;
    if (wid >= n) return;
    int h = lane >> 4, d = lane & 15;
    const float* qp = q + (size_t)wid * 128 + h * 32;
    const float* wp = We + (size_t)d * 128 + h * 32;
    float s = 0.f;
    #pragma unroll
    for (int c4 = 0; c4 < 8; ++c4) {
        float4 a = *(const float4*)&qp[c4 * 4];
        float4 b = *(const float4*)&wp[c4 * 4];
        s += a.x * b.x + a.y * b.y + a.z * b.z + a.w * b.w;
    }
    t[(size_t)wid * 64 + lane] = s;
}

// ---------------------------------------------------------------------------
// CSR build: histogram -> scan (3 kernels) -> scatter
// ---------------------------------------------------------------------------
__global__ void hist_kernel(const int* __restrict__ rows, int* __restrict__ counts, int e)
{
    int i = blockIdx.x * blockDim.x + threadIdx.x;
    if (i < e) atomicAdd(&counts[rows[i]], 1);
}

__global__ __launch_bounds__(1024) void scan1_kernel(int* __restrict__ data,
                                                     int* __restrict__ bsum, int n)
{
    __shared__ int s[1024];
    int i = blockIdx.x * 1024 + threadIdx.x;
    int v = (i < n) ? data[i] : 0;
    s[threadIdx.x] = v;
    __syncthreads();
    for (int offd = 1; offd < 1024; offd <<= 1) {
        int add = (threadIdx.x >= offd) ? s[threadIdx.x - offd] : 0;
        __syncthreads();
        s[threadIdx.x] += add;
        __syncthreads();
    }
    if (i < n) data[i] = s[threadIdx.x];
    if (threadIdx.x == 1023) bsum[blockIdx.x] = s[1023];
}

__global__ void scan2_kernel(const int* __restrict__ bsum, int* __restrict__ bofs, int nb)
{
    if (threadIdx.x == 0 && blockIdx.x == 0) {
        int a = 0;
        for (int i = 0; i < nb; ++i) { bofs[i] = a; a += bsum[i]; }
    }
}

__global__ __launch_bounds__(1024) void scan3_kernel(const int* __restrict__ incl,
                                                     const int* __restrict__ bofs,
                                                     int* __restrict__ offsets, int n)
{
    int i = blockIdx.x * 1024 + threadIdx.x;
    if (i == 0) offsets[0] = 0;
    if (i < n) offsets[i + 1] = incl[i] + bofs[blockIdx.x];
}

// Writes {src, eid} packed in CSR order — agg then loads one dwordx2.
__global__ void scatter_kernel(const int* __restrict__ rows, const int* __restrict__ cols,
                               const int* __restrict__ offsets, int* __restrict__ cursor,
                               int2* __restrict__ csr_se, int e)
{
    int i = blockIdx.x * blockDim.x + threadIdx.x;
    if (i < e) {
        int r = rows[i];
        int p = atomicAdd(&cursor[r], 1);
        csr_se[offsets[r] + p] = make_int2(cols[i], i);
    }
}

// ---------------------------------------------------------------------------
// Aggregation: one wave per destination node, 4 EDGES IN PARALLEL.
// lane = es*16 + h*4 + cq : es = edge slot (0..3), h = head (0..3),
// cq = channel quad (0..3). Lane owns channels c0 = h*32+cq*8 .. +8 of its
// edge slot. Logit reduce = 2 shuffles over cq; per-node cross-es reduce at
// the end. Fused beta-gate epilogue.
// ---------------------------------------------------------------------------
__global__ __launch_bounds__(256) void agg_kernel(
    const float* __restrict__ q, const uint* __restrict__ kv,
    const float* __restrict__ t, const float* __restrict__ xskip,
    const float* __restrict__ ea, const int2* __restrict__ csr_se,
    const int* __restrict__ offsets, const float* __restrict__ Wbeta,
    float* __restrict__ out, int n)
{
    int wid = (blockIdx.x * blockDim.x + threadIdx.x) >> 6;
    int lane = threadIdx.x & 63;
    if (wid >= n) return;
    const int es = lane >> 4;
    const int h  = (lane >> 2) & 3;
    const int cq = lane & 3;
    const int c0 = h * 32 + cq * 8;

    float qv[8];
    *(float4*)&qv[0] = *(const float4*)&q[(size_t)wid * 128 + c0];
    *(float4*)&qv[4] = *(const float4*)&q[(size_t)wid * 128 + c0 + 4];
    float tv[4];
    *(float4*)&tv[0] = *(const float4*)&t[(size_t)wid * 64 + h * 16 + cq * 4];

    const int beg = offsets[wid], end = offsets[wid + 1];
    const float scale = 0.17677669529663687f;  // 1/sqrt(32)

    float denom = 0.f;
    float acc[8];
    #pragma unroll
    for (int j = 0; j < 8; ++j) acc[j] = 0.f;

    for (int i = beg; i < end; i += 4) {
        int idx = i + es;
        bool valid = idx < end;
        int cidx = valid ? idx : end - 1;
        int2 se = csr_se[cidx];
        const uint* krow = kv + (size_t)se.x * 128 + h * 16 + cq * 4;
        uint4 kp = *(const uint4*)krow;
        uint4 vp = *(const uint4*)(krow + 64);
        float4 eav = *(const float4*)&ea[(size_t)se.y * 16 + cq * 4];

        float part = qv[0] * bflo(kp.x) + qv[1] * bfhi(kp.x)
                   + qv[2] * bflo(kp.y) + qv[3] * bfhi(kp.y)
                   + qv[4] * bflo(kp.z) + qv[5] * bfhi(kp.z)
                   + qv[6] * bflo(kp.w) + qv[7] * bfhi(kp.w)
                   + eav.x * tv[0] + eav.y * tv[1]
                   + eav.z * tv[2] + eav.w * tv[3];
        part += __shfl_xor(part, 1);
        part += __shfl_xor(part, 2);
        float p = valid ? __expf(part * scale) : 0.f;
        denom += p;
        acc[0] += p * bflo(vp.x); acc[1] += p * bfhi(vp.x);
        acc[2] += p * bflo(vp.y); acc[3] += p * bfhi(vp.y);
        acc[4] += p * bflo(vp.z); acc[5] += p * bfhi(vp.z);
        acc[6] += p * bflo(vp.w); acc[7] += p * bfhi(vp.w);
    }

    // cross-edge-slot reduction (lanes 16 apart)
    denom += __shfl_xor(denom, 16);
    denom += __shfl_xor(denom, 32);
    #pragma unroll
    for (int j = 0; j < 8; ++j) {
        acc[j] += __shfl_xor(acc[j], 16);
        acc[j] += __shfl_xor(acc[j], 32);
    }

    float inv = 1.f / (denom * 0.25f + 1e-16f);  // denom counted 4x (cq replicas)... no:
    // NOTE: each cq lane accumulated the SAME p (per (es,h)); cross-es reduce sums
    // 4 es slots -> denom is the true per-head sum, NOT 4x. Undo the line above.
    inv = 1.f / (denom + 1e-16f);

    float o[8];
    #pragma unroll
    for (int j = 0; j < 8; ++j) o[j] = acc[j] * inv;

    float xsv[8];
    *(float4*)&xsv[0] = *(const float4*)&xskip[(size_t)wid * 128 + c0];
    *(float4*)&xsv[4] = *(const float4*)&xskip[(size_t)wid * 128 + c0 + 4];

    float bp = 0.f;
    #pragma unroll
    for (int j = 0; j < 8; ++j) {
        bp += o[j]   * Wbeta[c0 + j]
            + xsv[j] * Wbeta[128 + c0 + j]
            + (o[j] - xsv[j]) * Wbeta[256 + c0 + j];
    }
    bp += __shfl_xor(bp, 1);
    bp += __shfl_xor(bp, 2);
    bp += __shfl_xor(bp, 4);
    bp += __shfl_xor(bp, 8);
    float beta = 1.f / (1.f + __expf(-bp));

    if (es == 0) {
        float r[8];
        #pragma unroll
        for (int j = 0; j < 8; ++j) r[j] = beta * xsv[j] + (1.f - beta) * o[j];
        *(float4*)&out[(size_t)wid * 128 + c0]     = make_float4(r[0], r[1], r[2], r[3]);
        *(float4*)&out[(size_t)wid * 128 + c0 + 4] = make_float4(r[4], r[5], r[6], r[7]);
    }
}

// ---------------------------------------------------------------------------
extern "C" void kernel_launch(void* const* d_in, const int* in_sizes, int n_in,
                              void* d_out, int out_size, void* d_ws, size_t ws_size,
                              hipStream_t stream)
{
    const float* x     = (const float*)d_in[0];
    const float* ea    = (const float*)d_in[1];
    const int*   ei    = (const int*)d_in[2];   // [0:E)=row(dst), [E:2E)=col(src)
    const float* Wq    = (const float*)d_in[3];
    const float* bq    = (const float*)d_in[4];
    const float* Wk    = (const float*)d_in[5];
    const float* bk    = (const float*)d_in[6];
    const float* Wv    = (const float*)d_in[7];
    const float* bv    = (const float*)d_in[8];
    const float* We    = (const float*)d_in[9];
    const float* Wsk   = (const float*)d_in[10];
    const float* bsk   = (const float*)d_in[11];
    const float* Wbeta = (const float*)d_in[12];
    float* out = (float*)d_out;

    const int N = in_sizes[0] / 128;
    const int E = in_sizes[1] / 16;

    char* base = (char*)d_ws;
    size_t off = 0;
    auto alloc = [&](size_t bytes) -> void* {
        void* p = base + off;
        off += (bytes + 255) & ~(size_t)255;
        return p;
    };
    int*    tmp     = (int*)alloc((size_t)N * 4);        // counts -> inclusive scan
    int*    cursor  = (int*)alloc((size_t)N * 4);
    int*    offsets = (int*)alloc((size_t)(N + 1) * 4);
    int*    bsum    = (int*)alloc(4096 * 4);
    int*    bofs    = (int*)alloc(4096 * 4);
    int2*   csr_se  = (int2*)alloc((size_t)E * 8);
    float*  qbuf    = (float*)alloc((size_t)N * 128 * 4);
    float*  sbuf    = (float*)alloc((size_t)N * 128 * 4);
    float*  tbuf    = (float*)alloc((size_t)N * 64 * 4);
    uint*   kvbuf   = (uint*)alloc((size_t)N * 128 * 4); // bf16x2: k [0..63], v [64..127]
    (void)ws_size; (void)n_in; (void)out_size;

    hipMemsetAsync(tmp, 0, (size_t)N * 4, stream);
    hipMemsetAsync(cursor, 0, (size_t)N * 4, stream);

    dim3 lgrid((N + 63) / 64, 4);
    lin_kernel<<<lgrid, 256, 0, stream>>>(x, Wq, bq, Wk, bk, Wv, bv, Wsk, bsk,
                                          qbuf, kvbuf, sbuf, N);
    t_kernel<<<(N + 3) / 4, 256, 0, stream>>>(qbuf, We, tbuf, N);
    hist_kernel<<<(E + 255) / 256, 256, 0, stream>>>(ei, tmp, E);
    int nb = (N + 1023) / 1024;
    scan1_kernel<<<nb, 1024, 0, stream>>>(tmp, bsum, N);
    scan2_kernel<<<1, 64, 0, stream>>>(bsum, bofs, nb);
    scan3_kernel<<<nb, 1024, 0, stream>>>(tmp, bofs, offsets, N);
    scatter_kernel<<<(E + 255) / 256, 256, 0, stream>>>(ei, ei + E, offsets, cursor,
                                                        csr_se, E);
    agg_kernel<<<(N + 3) / 4, 256, 0, stream>>>(qbuf, kvbuf, tbuf, sbuf, ea,
                                                csr_se, offsets, Wbeta, out, N);
}

// Round 4
// 677.158 us; speedup vs baseline: 1.4878x; 1.1934x over previous
//
#include <hip/hip_runtime.h>
#include <stdint.h>

typedef unsigned int uint;
typedef unsigned short ushort;

typedef __attribute__((ext_vector_type(8))) short bf16x8;   // 8 bf16 = 4 VGPRs
typedef __attribute__((ext_vector_type(16))) float f32x16;  // MFMA 32x32 acc

__device__ inline float bflo(uint u) {
    union { uint x; float f; } z; z.x = u << 16; return z.f;
}
__device__ inline float bfhi(uint u) {
    union { uint x; float f; } z; z.x = u & 0xffff0000u; return z.f;
}
__device__ inline ushort f2bf(float f) {
    union { float f; uint u; } x; x.f = f;
    uint r = (x.u + 0x7fffu + ((x.u >> 16) & 1u)) >> 16;
    return (ushort)r;
}

// ---------------------------------------------------------------------------
// pack_x: x (fp32 row-major) -> bf16 fragment-ordered tiles:
//   xfrag chunk index o = tile*2048 + kb*128 + m   (chunk = 16B = 8 bf16)
//   holds x[tile*128+m][kb*8 .. kb*8+8), zero-padded past n rows.
// This makes MFMA A-fragment loads plain coalesced dwordx4 from global.
// ---------------------------------------------------------------------------
__global__ __launch_bounds__(256) void pack_x(const float* __restrict__ x,
                                              uint4* __restrict__ xfrag,
                                              int n, int nchunks)
{
    int o = blockIdx.x * 256 + threadIdx.x;
    if (o >= nchunks) return;
    int m    = o & 127;
    int kb   = (o >> 7) & 15;
    int tile = o >> 11;
    int row  = tile * 128 + m;
    float4 lo = make_float4(0.f, 0.f, 0.f, 0.f);
    float4 hi = make_float4(0.f, 0.f, 0.f, 0.f);
    if (row < n) {
        lo = *(const float4*)&x[(size_t)row * 128 + kb * 8];
        hi = *(const float4*)&x[(size_t)row * 128 + kb * 8 + 4];
    }
    uint4 ov;
    ov.x = (uint)f2bf(lo.x) | ((uint)f2bf(lo.y) << 16);
    ov.y = (uint)f2bf(lo.z) | ((uint)f2bf(lo.w) << 16);
    ov.z = (uint)f2bf(hi.x) | ((uint)f2bf(hi.y) << 16);
    ov.w = (uint)f2bf(hi.z) | ((uint)f2bf(hi.w) << 16);
    xfrag[o] = ov;
}

// ---------------------------------------------------------------------------
// pack_w: W_j (fp32 [K=128][N=128] row-major) -> bf16 B-fragment order:
//   wfrag chunk o = j*2048 + kb*128 + n, holds W_j[kb*8 .. +8)[n] (k-column).
// ---------------------------------------------------------------------------
__global__ __launch_bounds__(256) void pack_w(
    const float* __restrict__ W0, const float* __restrict__ W1,
    const float* __restrict__ W2, const float* __restrict__ W3,
    uint4* __restrict__ wfrag)
{
    int o = blockIdx.x * 256 + threadIdx.x;   // 4*16*128 = 8192 chunks
    if (o >= 8192) return;
    int nn = o & 127;
    int kb = (o >> 7) & 15;
    int j  = o >> 11;
    const float* W = (j == 0) ? W0 : (j == 1) ? W1 : (j == 2) ? W2 : W3;
    float v[8];
    #pragma unroll
    for (int i = 0; i < 8; ++i) v[i] = W[(size_t)(kb * 8 + i) * 128 + nn];
    uint4 ov;
    ov.x = (uint)f2bf(v[0]) | ((uint)f2bf(v[1]) << 16);
    ov.y = (uint)f2bf(v[2]) | ((uint)f2bf(v[3]) << 16);
    ov.z = (uint)f2bf(v[4]) | ((uint)f2bf(v[5]) << 16);
    ov.w = (uint)f2bf(v[6]) | ((uint)f2bf(v[7]) << 16);
    wfrag[o] = ov;
}

// ---------------------------------------------------------------------------
// lin_mfma: per block, 128 rows x all 4 weight matrices (512 cols), K=128.
// Wave w owns rows w*32..w*32+31; A-frags (8 k-steps) live in VGPRs and are
// reused across all 4 GEMMs. No LDS, no barriers, no bank conflicts.
// v_mfma_f32_32x32x16_bf16; C/D: col=lane&31, row=(reg&3)+8*(reg>>2)+4*(lane>>5).
// Outputs bf16-pair packed: q [n][64], kv [n][128] (k 0..63 | v 64..127),
// skip [n][64].
// ---------------------------------------------------------------------------
__global__ __launch_bounds__(256) void lin_mfma(
    const uint4* __restrict__ xfrag, const uint4* __restrict__ wfrag,
    const float* __restrict__ bq, const float* __restrict__ bk,
    const float* __restrict__ bv, const float* __restrict__ bs,
    uint* __restrict__ qout, uint* __restrict__ kvout, uint* __restrict__ sout,
    int n)
{
    const int tile = blockIdx.x;
    const int w  = threadIdx.x >> 6;
    const int l  = threadIdx.x & 63;
    const int lm = l & 31, lh = l >> 5;

    // A fragments: a[ks] = x[m = tile*128 + w*32 + lm][k = ks*16 + lh*8 .. +8)
    bf16x8 a[8];
    const uint4* ap = xfrag + (size_t)tile * 2048 + lh * 128 + w * 32 + lm;
    #pragma unroll
    for (int ks = 0; ks < 8; ++ks) a[ks] = *(const bf16x8*)(ap + ks * 256);

    const int rowbase = tile * 128 + w * 32 + 4 * lh;

    #pragma unroll
    for (int j = 0; j < 4; ++j) {
        const float* bias = (j == 0) ? bq : (j == 1) ? bk : (j == 2) ? bv : bs;
        uint* dst; int stride, cbase;
        if (j == 0)      { dst = qout;  stride = 64;  cbase = 0;  }
        else if (j == 1) { dst = kvout; stride = 128; cbase = 0;  }
        else if (j == 2) { dst = kvout; stride = 128; cbase = 64; }
        else             { dst = sout;  stride = 64;  cbase = 0;  }

        #pragma unroll
        for (int np = 0; np < 2; ++np) {       // ni pair {2np, 2np+1}
            const uint4* bp0 = wfrag + (size_t)j * 2048 + lh * 128 + (np * 2) * 32 + lm;
            f32x16 c0, c1;
            #pragma unroll
            for (int i = 0; i < 16; ++i) { c0[i] = 0.f; c1[i] = 0.f; }
            #pragma unroll
            for (int ks = 0; ks < 8; ++ks) {
                bf16x8 B0 = *(const bf16x8*)(bp0 + ks * 256);
                bf16x8 B1 = *(const bf16x8*)(bp0 + 32 + ks * 256);
                c0 = __builtin_amdgcn_mfma_f32_32x32x16_bf16(a[ks], B0, c0, 0, 0, 0);
                c1 = __builtin_amdgcn_mfma_f32_32x32x16_bf16(a[ks], B1, c1, 0, 0, 0);
            }
            #pragma unroll
            for (int t = 0; t < 2; ++t) {
                f32x16 cc = t ? c1 : c0;
                int gc = (np * 2 + t) * 32 + lm;
                float bl = bias[gc];
                #pragma unroll
                for (int r = 0; r < 16; ++r) {
                    float val = cc[r] + bl;
                    float partner = __shfl_xor(val, 1);
                    int gr = rowbase + (r & 3) + 8 * (r >> 2);
                    if (!(lm & 1) && gr < n) {
                        uint pk = (uint)f2bf(val) | ((uint)f2bf(partner) << 16);
                        dst[(size_t)gr * stride + cbase + (gc >> 1)] = pk;
                    }
                }
            }
        }
    }
}

// ---------------------------------------------------------------------------
// t[n,h,d] = sum_c We[d, h*32+c] * q[n, h*32+c]  — one wave per node,
// lane = h*16 + d. q read as packed bf16 pairs.
// ---------------------------------------------------------------------------
__global__ __launch_bounds__(256) void t_kernel(const uint* __restrict__ qb,
                                                const float* __restrict__ We,
                                                float* __restrict__ t, int n)
{
    int wid = (blockIdx.x * blockDim.x + threadIdx.x) >> 6;
    int lane = threadIdx.x & 63;
    if (wid >= n) return;
    int h = lane >> 4, d = lane & 15;
    const uint* qp = qb + (size_t)wid * 64 + h * 16;
    const float* wp = We + (size_t)d * 128 + h * 32;
    float s = 0.f;
    #pragma unroll
    for (int j4 = 0; j4 < 16; j4 += 4) {
        uint4 u = *(const uint4*)(qp + j4);
        float4 wA = *(const float4*)&wp[2 * j4];
        float4 wB = *(const float4*)&wp[2 * j4 + 4];
        s += bflo(u.x) * wA.x + bfhi(u.x) * wA.y
           + bflo(u.y) * wA.z + bfhi(u.y) * wA.w
           + bflo(u.z) * wB.x + bfhi(u.z) * wB.y
           + bflo(u.w) * wB.z + bfhi(u.w) * wB.w;
    }
    t[(size_t)wid * 64 + lane] = s;
}

// ---------------------------------------------------------------------------
// CSR build: histogram -> scan (3 kernels) -> scatter
// ---------------------------------------------------------------------------
__global__ void hist_kernel(const int* __restrict__ rows, int* __restrict__ counts, int e)
{
    int i = blockIdx.x * blockDim.x + threadIdx.x;
    if (i < e) atomicAdd(&counts[rows[i]], 1);
}

__global__ __launch_bounds__(1024) void scan1_kernel(int* __restrict__ data,
                                                     int* __restrict__ bsum, int n)
{
    __shared__ int s[1024];
    int i = blockIdx.x * 1024 + threadIdx.x;
    int v = (i < n) ? data[i] : 0;
    s[threadIdx.x] = v;
    __syncthreads();
    for (int offd = 1; offd < 1024; offd <<= 1) {
        int add = (threadIdx.x >= offd) ? s[threadIdx.x - offd] : 0;
        __syncthreads();
        s[threadIdx.x] += add;
        __syncthreads();
    }
    if (i < n) data[i] = s[threadIdx.x];
    if (threadIdx.x == 1023) bsum[blockIdx.x] = s[1023];
}

// parallel block-sums scan (nb <= 1024), exclusive
__global__ __launch_bounds__(1024) void scan2_kernel(const int* __restrict__ bsum,
                                                     int* __restrict__ bofs, int nb)
{
    __shared__ int s[1024];
    int tid = threadIdx.x;
    int v = (tid < nb) ? bsum[tid] : 0;
    s[tid] = v;
    __syncthreads();
    for (int o = 1; o < 1024; o <<= 1) {
        int add = (tid >= o) ? s[tid - o] : 0;
        __syncthreads();
        s[tid] += add;
        __syncthreads();
    }
    if (tid < nb) bofs[tid] = s[tid] - v;
}

__global__ __launch_bounds__(1024) void scan3_kernel(const int* __restrict__ incl,
                                                     const int* __restrict__ bofs,
                                                     int* __restrict__ offsets, int n)
{
    int i = blockIdx.x * 1024 + threadIdx.x;
    if (i == 0) offsets[0] = 0;
    if (i < n) offsets[i + 1] = incl[i] + bofs[blockIdx.x];
}

// Writes {src, eid} packed in CSR order — agg then loads one dwordx2.
__global__ void scatter_kernel(const int* __restrict__ rows, const int* __restrict__ cols,
                               const int* __restrict__ offsets, int* __restrict__ cursor,
                               int2* __restrict__ csr_se, int e)
{
    int i = blockIdx.x * blockDim.x + threadIdx.x;
    if (i < e) {
        int r = rows[i];
        int p = atomicAdd(&cursor[r], 1);
        csr_se[offsets[r] + p] = make_int2(cols[i], i);
    }
}

// ---------------------------------------------------------------------------
// Aggregation: one wave per destination node, 4 edges in parallel.
// lane = es*16 + h*4 + cq. Lane owns channels c0 = h*32+cq*8 .. +8 of its
// edge slot. q / xskip read as packed bf16 pairs.
// ---------------------------------------------------------------------------
__global__ __launch_bounds__(256) void agg_kernel(
    const uint* __restrict__ qb, const uint* __restrict__ kv,
    const float* __restrict__ t, const uint* __restrict__ sb,
    const float* __restrict__ ea, const int2* __restrict__ csr_se,
    const int* __restrict__ offsets, const float* __restrict__ Wbeta,
    float* __restrict__ out, int n)
{
    int wid = (blockIdx.x * blockDim.x + threadIdx.x) >> 6;
    int lane = threadIdx.x & 63;
    if (wid >= n) return;
    const int es = lane >> 4;
    const int h  = (lane >> 2) & 3;
    const int cq = lane & 3;
    const int c0 = h * 32 + cq * 8;

    uint4 uq = *(const uint4*)&qb[(size_t)wid * 64 + h * 16 + cq * 4];
    float qv[8] = { bflo(uq.x), bfhi(uq.x), bflo(uq.y), bfhi(uq.y),
                    bflo(uq.z), bfhi(uq.z), bflo(uq.w), bfhi(uq.w) };
    float tv[4];
    *(float4*)&tv[0] = *(const float4*)&t[(size_t)wid * 64 + h * 16 + cq * 4];

    const int beg = offsets[wid], end = offsets[wid + 1];
    const float scale = 0.17677669529663687f;  // 1/sqrt(32)

    float denom = 0.f;
    float acc[8];
    #pragma unroll
    for (int j = 0; j < 8; ++j) acc[j] = 0.f;

    for (int i = beg; i < end; i += 4) {
        int idx = i + es;
        bool valid = idx < end;
        int cidx = valid ? idx : end - 1;
        int2 se = csr_se[cidx];
        const uint* krow = kv + (size_t)se.x * 128 + h * 16 + cq * 4;
        uint4 kp = *(const uint4*)krow;
        uint4 vp = *(const uint4*)(krow + 64);
        float4 eav = *(const float4*)&ea[(size_t)se.y * 16 + cq * 4];

        float part = qv[0] * bflo(kp.x) + qv[1] * bfhi(kp.x)
                   + qv[2] * bflo(kp.y) + qv[3] * bfhi(kp.y)
                   + qv[4] * bflo(kp.z) + qv[5] * bfhi(kp.z)
                   + qv[6] * bflo(kp.w) + qv[7] * bfhi(kp.w)
                   + eav.x * tv[0] + eav.y * tv[1]
                   + eav.z * tv[2] + eav.w * tv[3];
        part += __shfl_xor(part, 1);
        part += __shfl_xor(part, 2);
        float p = valid ? __expf(part * scale) : 0.f;
        denom += p;
        acc[0] += p * bflo(vp.x); acc[1] += p * bfhi(vp.x);
        acc[2] += p * bflo(vp.y); acc[3] += p * bfhi(vp.y);
        acc[4] += p * bflo(vp.z); acc[5] += p * bfhi(vp.z);
        acc[6] += p * bflo(vp.w); acc[7] += p * bfhi(vp.w);
    }

    denom += __shfl_xor(denom, 16);
    denom += __shfl_xor(denom, 32);
    #pragma unroll
    for (int j = 0; j < 8; ++j) {
        acc[j] += __shfl_xor(acc[j], 16);
        acc[j] += __shfl_xor(acc[j], 32);
    }

    float inv = 1.f / (denom + 1e-16f);
    float o[8];
    #pragma unroll
    for (int j = 0; j < 8; ++j) o[j] = acc[j] * inv;

    uint4 us = *(const uint4*)&sb[(size_t)wid * 64 + h * 16 + cq * 4];
    float xsv[8] = { bflo(us.x), bfhi(us.x), bflo(us.y), bfhi(us.y),
                     bflo(us.z), bfhi(us.z), bflo(us.w), bfhi(us.w) };

    float bp = 0.f;
    #pragma unroll
    for (int j = 0; j < 8; ++j) {
        bp += o[j]   * Wbeta[c0 + j]
            + xsv[j] * Wbeta[128 + c0 + j]
            + (o[j] - xsv[j]) * Wbeta[256 + c0 + j];
    }
    bp += __shfl_xor(bp, 1);
    bp += __shfl_xor(bp, 2);
    bp += __shfl_xor(bp, 4);
    bp += __shfl_xor(bp, 8);
    float beta = 1.f / (1.f + __expf(-bp));

    if (es == 0) {
        float r[8];
        #pragma unroll
        for (int j = 0; j < 8; ++j) r[j] = beta * xsv[j] + (1.f - beta) * o[j];
        *(float4*)&out[(size_t)wid * 128 + c0]     = make_float4(r[0], r[1], r[2], r[3]);
        *(float4*)&out[(size_t)wid * 128 + c0 + 4] = make_float4(r[4], r[5], r[6], r[7]);
    }
}

// ---------------------------------------------------------------------------
extern "C" void kernel_launch(void* const* d_in, const int* in_sizes, int n_in,
                              void* d_out, int out_size, void* d_ws, size_t ws_size,
                              hipStream_t stream)
{
    const float* x     = (const float*)d_in[0];
    const float* ea    = (const float*)d_in[1];
    const int*   ei    = (const int*)d_in[2];   // [0:E)=row(dst), [E:2E)=col(src)
    const float* Wq    = (const float*)d_in[3];
    const float* bq    = (const float*)d_in[4];
    const float* Wk    = (const float*)d_in[5];
    const float* bk    = (const float*)d_in[6];
    const float* Wv    = (const float*)d_in[7];
    const float* bv    = (const float*)d_in[8];
    const float* We    = (const float*)d_in[9];
    const float* Wsk   = (const float*)d_in[10];
    const float* bsk   = (const float*)d_in[11];
    const float* Wbeta = (const float*)d_in[12];
    float* out = (float*)d_out;

    const int N = in_sizes[0] / 128;
    const int E = in_sizes[1] / 16;
    const int NT = (N + 127) / 128;         // 128-row tiles
    const int nchunks = NT * 2048;

    char* base = (char*)d_ws;
    size_t off = 0;
    auto alloc = [&](size_t bytes) -> void* {
        void* p = base + off;
        off += (bytes + 255) & ~(size_t)255;
        return p;
    };
    int*    tmp     = (int*)alloc((size_t)N * 4);
    int*    cursor  = (int*)alloc((size_t)N * 4);
    int*    offsets = (int*)alloc((size_t)(N + 1) * 4);
    int*    bsum    = (int*)alloc(4096 * 4);
    int*    bofs    = (int*)alloc(4096 * 4);
    int2*   csr_se  = (int2*)alloc((size_t)E * 8);
    uint4*  xfrag   = (uint4*)alloc((size_t)nchunks * 16);
    uint4*  wfrag   = (uint4*)alloc((size_t)8192 * 16);
    uint*   qbuf    = (uint*)alloc((size_t)N * 64 * 4);   // bf16 pairs
    uint*   sbuf    = (uint*)alloc((size_t)N * 64 * 4);   // bf16 pairs
    float*  tbuf    = (float*)alloc((size_t)N * 64 * 4);
    uint*   kvbuf   = (uint*)alloc((size_t)N * 128 * 4);  // bf16: k [0..63], v [64..127]
    (void)ws_size; (void)n_in; (void)out_size;

    hipMemsetAsync(tmp, 0, (size_t)N * 4, stream);
    hipMemsetAsync(cursor, 0, (size_t)N * 4, stream);

    pack_x<<<(nchunks + 255) / 256, 256, 0, stream>>>(x, xfrag, N, nchunks);
    pack_w<<<32, 256, 0, stream>>>(Wq, Wk, Wv, Wsk, wfrag);
    lin_mfma<<<NT, 256, 0, stream>>>(xfrag, wfrag, bq, bk, bv, bsk,
                                     qbuf, kvbuf, sbuf, N);
    t_kernel<<<(N + 3) / 4, 256, 0, stream>>>(qbuf, We, tbuf, N);
    hist_kernel<<<(E + 255) / 256, 256, 0, stream>>>(ei, tmp, E);
    int nb = (N + 1023) / 1024;
    scan1_kernel<<<nb, 1024, 0, stream>>>(tmp, bsum, N);
    scan2_kernel<<<1, 1024, 0, stream>>>(bsum, bofs, nb);
    scan3_kernel<<<nb, 1024, 0, stream>>>(tmp, bofs, offsets, N);
    scatter_kernel<<<(E + 255) / 256, 256, 0, stream>>>(ei, ei + E, offsets, cursor,
                                                        csr_se, E);
    agg_kernel<<<(N + 3) / 4, 256, 0, stream>>>(qbuf, kvbuf, tbuf, sbuf, ea,
                                                csr_se, offsets, Wbeta, out, N);
}